// Round 12
// baseline (135.123 us; speedup 1.0000x reference)
//
#include <hip/hip_runtime.h>
#include <stdint.h>
#include <limits.h>

#define BATCH 4
#define N1D   2048
#define N2D   8192
#define NSAMP 32
#define NKP   15
#define CIN   64
#define COUT  128

#define RAD2    0.01f     // RADIUS^2
#define INV_EXT 25.0f     // 1 / EXTENT (EXTENT = 0.04)
#define BN_EPS  1e-5f
#define CMARG   0.1000001f  // cell-range margin (covers f32 rounding)

#define NWAVE 2                 // waves per block (block = 128)
#define QPB   NWAVE             // 2 queries per block, 1 per wave
#define CAP   40                // slots per cell (Poisson mean 8.2 -> no overflow)
#define MAXC  80                // candidate cap
#define NPF   4                 // prefetch depth in candidate walk

// ---- ws layout (in floats) ----
#define WS_FEATT  0                 // float [B*N2*CIN]             2097152
#define WS_OUT2   2097152           // float [B*COUT*N1]            1048576
#define WS_CNT    3145728           // int   [B*1024] cell counts      4096
#define WS_BPTS   3149824           // float4[B*1024*CAP] binned     655360

__device__ __forceinline__ int cell_of(float x, float y, float z) {
  int cx = (int)(x*10.f); cx = cx < 0 ? 0 : (cx > 9 ? 9 : cx);
  int cy = (int)(y*10.f); cy = cy < 0 ? 0 : (cy > 9 ? 9 : cy);
  int cz = (int)(z*10.f); cz = cz < 0 ? 0 : (cz > 9 ? 9 : cz);
  return (cx*10 + cy)*10 + cz;
}

// ---------------------------------------------------------------------------
// prep: blocks 0-511 feature transpose (LDS-tiled);
//       blocks 512-639 direct fixed-capacity binning (atomic slot claim).
// grid = 640 x 256.
// ---------------------------------------------------------------------------
__global__ __launch_bounds__(256) void pg_prep(
    const float* __restrict__ sxyz, const float* __restrict__ smask,
    const float* __restrict__ sfeat, float* __restrict__ featT,
    int* __restrict__ cellCnt, float4* __restrict__ bpts)
{
  __shared__ float tile[64*65];
  const int t  = threadIdx.x;
  const int bt = blockIdx.x;

  if (bt >= 512) {        // ---- binning: 1 point per thread ----
    const int idx = bt - 512;                // [0,128)
    const int bb  = idx >> 5;
    const int i   = ((idx & 31) << 8) + t;   // [0,8192)
    if (smask[bb*N2D + i] > 0.f) {
      const float* p = sxyz + ((size_t)bb*N2D + i)*3;
      const float px = p[0], py = p[1], pz = p[2];
      const int cell = bb*1024 + cell_of(px, py, pz);
      const int pos = atomicAdd(&cellCnt[cell], 1);
      if (pos < CAP)
        bpts[(size_t)cell*CAP + pos] = make_float4(px, py, pz, __int_as_float(i));
    }
    return;
  }

  // ---- feature transpose tile ----
  const int b  = bt >> 7;
  const int j0 = (bt & 127) * 64;
  const float* src = sfeat + (size_t)(b*CIN)*N2D + j0;
#pragma unroll
  for (int i = 0; i < 4; ++i) {
    const int c  = i*16 + (t >> 4);
    const int j4 = (t & 15) * 4;
    const float4 v = *(const float4*)(src + (size_t)c*N2D + j4);
    tile[c*65 + j4+0] = v.x;
    tile[c*65 + j4+1] = v.y;
    tile[c*65 + j4+2] = v.z;
    tile[c*65 + j4+3] = v.w;
  }
  __syncthreads();
  float* dstb = featT + (size_t)(b*N2D + j0) * CIN;
#pragma unroll
  for (int r = 0; r < 4; ++r) {
    const int j  = r*16 + (t >> 4);
    const int c4 = (t & 15) * 4;
    float4 v;
    v.x = tile[(c4+0)*65 + j];
    v.y = tile[(c4+1)*65 + j];
    v.z = tile[(c4+2)*65 + j];
    v.w = tile[(c4+3)*65 + j];
    *(float4*)(dstb + j*CIN + c4) = v;
  }
}

// ---------------------------------------------------------------------------
// main: cell-walk ordered ball query + dense branchless kernel-point weights
// + weighted feature sum + fused 1x1 conv.
// grid = 4096 x 128 (2 waves/block, 1 query/wave) -> 16 WG/CU, fine-grain
// backfill, convoy = max-of-2 waves.  LDS ~8.9 KB -> 16 blocks/CU.
// ---------------------------------------------------------------------------
__global__ __launch_bounds__(128) void pg_main(
    const float* __restrict__ qxyz, const float* __restrict__ qmask,
    const float4* __restrict__ bpts, const int* __restrict__ cellCnt,
    const float* __restrict__ featT, const float* __restrict__ Kp,
    const float* __restrict__ KW, const float* __restrict__ Wout,
    const float* __restrict__ sxyz, float* __restrict__ out2)
{
  __shared__ __align__(16) float4 s_cand4[QPB][MAXC];  // candidate coords+j
  __shared__ __align__(16) int    s_candj[QPB][MAXC];  // candidate j
  __shared__ __align__(16) float4 s_sel[QPB][NSAMP];   // selected (x,y,z,j)
  __shared__ __align__(16) int    s_j[QPB][NSAMP];     // normalized idx
  __shared__ __align__(16) float  s_w[QPB*NSAMP*16];   // dense weights 4 KB
  __shared__ float                s_xq[QPB*68];        // conv x rows

  const int t    = threadIdx.x;
  const int lane = t & 63;
  const int wv   = t >> 6;
  const int gbase = blockIdx.x * QPB;        // 2048 % 2 == 0 -> single batch
  const int b     = gbase >> 11;
  const uint64_t lt = (1ull << lane) - 1ull;

  const int g = gbase + wv;                  // this wave's query
  const float qx = qxyz[g*3+0], qy = qxyz[g*3+1], qz = qxyz[g*3+2];

  // ---- phase 1: 3D-pruned per-cell segment walk ----
  int cq;
  {
    int cx0 = (int)((qx-CMARG)*10.f); if (cx0 < 0) cx0 = 0;
    int cx1 = (int)((qx+CMARG)*10.f); if (cx1 > 9) cx1 = 9;
    int cy0 = (int)((qy-CMARG)*10.f); if (cy0 < 0) cy0 = 0;
    int cy1 = (int)((qy+CMARG)*10.f); if (cy1 > 9) cy1 = 9;
    int cz0 = (int)((qz-CMARG)*10.f); if (cz0 < 0) cz0 = 0;
    int cz1 = (int)((qz+CMARG)*10.f); if (cz1 > 9) cz1 = 9;
    const int nz  = cz1 - cz0 + 1;
    const int nyz = (cy1 - cy0 + 1) * nz;
    const int ncl = (cx1 - cx0 + 1) * nyz;   // <= 27

    int len = 0, base = 0;
    if (lane < ncl) {
      int r = lane;
      const int cx = cx0 + r / nyz;  r %= nyz;
      const int cy = cy0 + r / nz;
      const int cz = cz0 + r % nz;
      // 3D AABB prune: min distance from q to cell box
      const float lox = cx*0.1f, loy = cy*0.1f, loz = cz*0.1f;
      const float dxc = fmaxf(fmaxf(lox - qx, qx - (lox+0.1f)), 0.f);
      const float dyc = fmaxf(fmaxf(loy - qy, qy - (loy+0.1f)), 0.f);
      const float dzc = fmaxf(fmaxf(loz - qz, qz - (loz+0.1f)), 0.f);
      if (dxc*dxc + dyc*dyc + dzc*dzc < RAD2) {
        const int cell = b*1024 + (cx*10 + cy)*10 + cz;
        const int cnt = cellCnt[cell];        // L2-hot 16 KB
        len  = cnt < CAP ? cnt : CAP;
        base = cell*CAP;
      }
    }
    int pc = len;                            // inclusive prefix over 64 lanes
#pragma unroll
    for (int off = 1; off < 64; off <<= 1) {
      int y = __shfl_up(pc, off);
      if (lane >= off) pc += y;
    }
    const int tot  = __shfl(pc, 63);
    const int excl = pc - len;
    const int sb   = base - excl;

    // broadcast 27-entry segment tables to SGPRs
    int segc[27], segb[27];
#pragma unroll
    for (int e = 0; e < 27; ++e) {
      const int ce = __builtin_amdgcn_readlane(excl, e);
      const int be = __builtin_amdgcn_readlane(sb,   e);
      segc[e] = (e < ncl) ? ce : INT_MAX;
      segb[e] = (e < ncl) ? be : 0;
    }

    int ccnt = 0;
    for (int base0 = 0; base0 < tot; base0 += 64*NPF) {
      float4 pt[NPF];
#pragma unroll
      for (int u = 0; u < NPF; ++u) {
        const int idx = base0 + u*64 + lane;
        if (idx < tot) {
          int bb2 = segb[0];                 // branchless segment select
#pragma unroll
          for (int e = 1; e < 27; ++e) if (segc[e] <= idx) bb2 = segb[e];
          pt[u] = bpts[bb2 + idx];
        }
      }
#pragma unroll
      for (int u = 0; u < NPF; ++u) {
        const int idx = base0 + u*64 + lane;
        bool ok = false;
        if (idx < tot) {
          const float dx = pt[u].x - qx, dy = pt[u].y - qy, dz = pt[u].z - qz;
          ok = (dx*dx + dy*dy + dz*dz) < RAD2;
        }
        const uint64_t m = __ballot(ok);
        if (ok) {
          const int pos = ccnt + __popcll(m & lt);
          if (pos < MAXC) {
            s_cand4[wv][pos] = pt[u];
            s_candj[wv][pos] = __float_as_int(pt[u].w);
          }
        }
        ccnt += (int)__popcll(m);
      }
    }
    const int C = ccnt < MAXC ? ccnt : MAXC;
    const int C4 = (C + 3) & ~3;
    if (C + lane < C4) s_candj[wv][C + lane] = INT_MAX;  // pad to x4

    // rank-select 32 smallest j via int4 LDS reads
    const int jA = (lane      < C) ? s_candj[wv][lane]      : INT_MAX;
    const int jB = (lane + 64 < C) ? s_candj[wv][lane + 64] : INT_MAX;
    int rA = 0, rB = 0;
    for (int e = 0; e < C4; e += 4) {
      const int4 v4 = *(const int4*)&s_candj[wv][e];
      rA += (v4.x < jA) + (v4.y < jA) + (v4.z < jA) + (v4.w < jA);
      rB += (v4.x < jB) + (v4.y < jB) + (v4.z < jB) + (v4.w < jB);
    }
    if (lane      < C && rA < NSAMP) s_sel[wv][rA] = s_cand4[wv][lane];
    if (lane + 64 < C && rB < NSAMP) s_sel[wv][rB] = s_cand4[wv][lane + 64];
    cq = C < NSAMP ? C : NSAMP;
  }

  // ---- phase 2-pre (wave-local): pad-normalize slots, publish s_j ----
  {
    const int s    = lane & 31;
    const int half = lane >> 5;
    float4 sel;
    if (cq > 0) {
      sel = s_sel[wv][s < cq ? s : 0];       // pad with first (min-j) neighbor
    } else {
      sel = make_float4(sxyz[(size_t)b*N2D*3+0], sxyz[(size_t)b*N2D*3+1],
                        sxyz[(size_t)b*N2D*3+2], __int_as_float(0));
    }
    if (half == 0) {
      s_sel[wv][s] = sel;                    // normalized coords for weights
      s_j[wv][s]   = __float_as_int(sel.w);
    }
  }

  // ---- issue all 32 feature gathers EARLY (overlap the weight math) ----
  float ft[NSAMP];
#pragma unroll
  for (int s = 0; s < NSAMP; ++s) {
    const int j = __builtin_amdgcn_readfirstlane(s_j[wv][s]);
    ft[s] = featT[(size_t)(b*N2D + j)*CIN + lane];
  }

  // ---- phase 2a (wave-local): dense weight rows ----
  {
    const int s    = lane & 31;
    const int half = lane >> 5;
    const float4 sel = s_sel[wv][s];
    const float rx = sel.x - qx;
    const float ry = sel.y - qy;
    const float rz = sel.z - qz;

    float w[8];
#pragma unroll
    for (int ki = 0; ki < 8; ++ki) {
      const int k  = half*8 + ki;
      const int kc = k < NKP-1 ? k : NKP-1;  // clamp for safe Kp read
      const float dx = rx - Kp[kc*3+0];
      const float dy = ry - Kp[kc*3+1];
      const float dz = rz - Kp[kc*3+2];
      float wk = fmaxf(1.0f - sqrtf(dx*dx+dy*dy+dz*dz)*INV_EXT, 0.0f);
      w[ki] = (k < NKP) ? wk : 0.0f;         // slot 15 = exact 0
    }
    float4* wrow = (float4*)&s_w[(wv*NSAMP + s)*16 + half*8];
    wrow[0] = make_float4(w[0], w[1], w[2], w[3]);
    wrow[1] = make_float4(w[4], w[5], w[6], w[7]);
  }

  // ---- phase 2b (wave-local, branchless): weighted feature aggregation ----
  {
    float kw[16];
#pragma unroll
    for (int k = 0; k < NKP; ++k) kw[k] = KW[k*CIN + lane];
    kw[15] = 0.0f;

    const float fpad = 1.0f - qmask[g];
    const int cqs = __builtin_amdgcn_readfirstlane(cq);

    float acc = 0.0f;
#pragma unroll
    for (int s = 0; s < NSAMP; ++s) {
      const float fm = ((s < cqs) ? 1.0f : 0.0f) + fpad;
      const float4* wp = (const float4*)&s_w[(wv*NSAMP + s)*16];
      const float4 w0 = wp[0], w1 = wp[1], w2 = wp[2], w3 = wp[3];
      float wsum;
      wsum = w0.x*kw[0];
      wsum = fmaf(w0.y, kw[1],  wsum);
      wsum = fmaf(w0.z, kw[2],  wsum);
      wsum = fmaf(w0.w, kw[3],  wsum);
      wsum = fmaf(w1.x, kw[4],  wsum);
      wsum = fmaf(w1.y, kw[5],  wsum);
      wsum = fmaf(w1.z, kw[6],  wsum);
      wsum = fmaf(w1.w, kw[7],  wsum);
      wsum = fmaf(w2.x, kw[8],  wsum);
      wsum = fmaf(w2.y, kw[9],  wsum);
      wsum = fmaf(w2.z, kw[10], wsum);
      wsum = fmaf(w2.w, kw[11], wsum);
      wsum = fmaf(w3.x, kw[12], wsum);
      wsum = fmaf(w3.y, kw[13], wsum);
      wsum = fmaf(w3.z, kw[14], wsum);
      wsum = fmaf(w3.w, kw[15], wsum);
      acc = fmaf(fm*wsum, ft[s], acc);
    }
    s_xq[wv*68 + lane] = acc;
  }
  __syncthreads();                           // the ONLY block barrier (2 waves)

  // ---- epilogue: fused 1x1 conv, 128 threads x 2 outputs, b128 reads ----
  // thread t: query slot qs = t&1, o-pair og = t>>1 (outputs 2og, 2og+1)
  {
    const int qs = t & 1;
    const int og = t >> 1;
    const int gq = gbase + qs;
    const int nn = gq & 2047;
    const float4* xr = (const float4*)&s_xq[qs*68];
    const float4* w0 = (const float4*)(Wout + (og*2+0)*CIN);
    const float4* w1 = (const float4*)(Wout + (og*2+1)*CIN);
    float a0 = 0.f, a1 = 0.f;
#pragma unroll
    for (int c4 = 0; c4 < 16; ++c4) {
      const float4 x4 = xr[c4];
      const float4 wa = w0[c4];
      const float4 wb = w1[c4];
      a0 = fmaf(wa.x, x4.x, fmaf(wa.y, x4.y, fmaf(wa.z, x4.z, fmaf(wa.w, x4.w, a0))));
      a1 = fmaf(wb.x, x4.x, fmaf(wb.y, x4.y, fmaf(wb.z, x4.z, fmaf(wb.w, x4.w, a1))));
    }
    float* ob = out2 + (size_t)(b*COUT + og*2)*N1D + nn;
    ob[0]   = a0;
    ob[N1D] = a1;
  }
}

// ---------------------------------------------------------------------------
// finish: per-(b,o) block; redundant stats + normalize own row.  512 x 256.
// ---------------------------------------------------------------------------
__global__ __launch_bounds__(256) void pg_finish(
    const float* __restrict__ out2, const float* __restrict__ gamma,
    const float* __restrict__ beta, float* __restrict__ dout)
{
  __shared__ float red[8];
  __shared__ float mv[2];
  const int t  = threadIdx.x;
  const int o  = blockIdx.x & 127;
  const int bb = blockIdx.x >> 7;
  float4 f[4][2];
  float s1 = 0.f, s2 = 0.f;
#pragma unroll
  for (int r = 0; r < BATCH; ++r) {
    const float4* p = (const float4*)(out2 + (size_t)(r*COUT + o)*N1D);
#pragma unroll
    for (int i = 0; i < 2; ++i) {
      const float4 x = p[i*256 + t];
      f[r][i] = x;
      s1 += x.x + x.y + x.z + x.w;
      s2 += x.x*x.x + x.y*x.y + x.z*x.z + x.w*x.w;
    }
  }
#pragma unroll
  for (int off = 32; off; off >>= 1) {
    s1 += __shfl_xor(s1, off);
    s2 += __shfl_xor(s2, off);
  }
  const int wv = t >> 6;
  if ((t & 63) == 0) { red[wv] = s1; red[4+wv] = s2; }
  __syncthreads();
  if (t == 0) {
    const float inv = 1.0f / (float)(BATCH*N1D);
    const float mean = (red[0]+red[1]+red[2]+red[3]) * inv;
    const float var  = (red[4]+red[5]+red[6]+red[7]) * inv - mean*mean;
    mv[0] = mean;
    mv[1] = rsqrtf(var + BN_EPS);
  }
  __syncthreads();
  const float mean = mv[0];
  const float ga = gamma[o] * mv[1];
  const float be = beta[o];
  float4* dp = (float4*)(dout + (size_t)(bb*COUT + o)*N1D);
#pragma unroll
  for (int i = 0; i < 2; ++i) {
    const float4 x = f[bb][i];
    float4 y;
    y.x = fmaxf((x.x - mean)*ga + be, 0.0f);
    y.y = fmaxf((x.y - mean)*ga + be, 0.0f);
    y.z = fmaxf((x.z - mean)*ga + be, 0.0f);
    y.w = fmaxf((x.w - mean)*ga + be, 0.0f);
    dp[i*256 + t] = y;
  }
}

extern "C" void kernel_launch(void* const* d_in, const int* in_sizes, int n_in,
                              void* d_out, int out_size, void* d_ws, size_t ws_size,
                              hipStream_t stream)
{
  const float* qxyz  = (const float*)d_in[0];
  const float* sxyz  = (const float*)d_in[1];
  const float* qmask = (const float*)d_in[2];
  const float* smask = (const float*)d_in[3];
  const float* sfeat = (const float*)d_in[4];
  const float* Kp    = (const float*)d_in[5];
  const float* KW    = (const float*)d_in[6];
  const float* Wout  = (const float*)d_in[7];
  const float* gamma = (const float*)d_in[8];
  const float* beta  = (const float*)d_in[9];
  float* ws = (float*)d_ws;
  float*  featT = ws + WS_FEATT;
  float*  out2  = ws + WS_OUT2;
  int*    cellC = (int*)(ws + WS_CNT);
  float4* bpts  = (float4*)(ws + WS_BPTS);
  float* dst    = (float*)d_out;

  hipMemsetAsync(cellC, 0, BATCH*1024*sizeof(int), stream);
  pg_prep  <<<640,  256, 0, stream>>>(sxyz, smask, sfeat, featT, cellC, bpts);
  pg_main  <<<4096, 128, 0, stream>>>(qxyz, qmask, bpts, cellC, featT,
                                      Kp, KW, Wout, sxyz, out2);
  pg_finish<<<512,  256, 0, stream>>>(out2, gamma, beta, dst);
}

// Round 13
// 123.477 us; speedup vs baseline: 1.0943x; 1.0943x over previous
//
#include <hip/hip_runtime.h>
#include <stdint.h>
#include <limits.h>

#define BATCH 4
#define N1D   2048
#define N2D   8192
#define NSAMP 32
#define NKP   15
#define CIN   64
#define COUT  128

#define RAD2    0.01f     // RADIUS^2
#define INV_EXT 25.0f     // 1 / EXTENT (EXTENT = 0.04)
#define BN_EPS  1e-5f
#define CMARG   0.1000001f  // cell-range margin (covers f32 rounding)

#define NWAVE 4                 // waves per block (block = 256)
#define QPB   NWAVE             // 4 queries per block, 1 per wave
#define CAP   40                // slots per cell (Poisson mean 8.2 -> no overflow)
#define MAXC  72                // candidate cap (ball count mean ~34, +6.5 sigma)
#define NPF   4                 // prefetch depth in candidate walk
#define WST   20                // s_w row stride (floats): 80B, 16B-aligned,
                                // banks spread 8 quad-groups -> 4-way writes

// ---- ws layout (in floats) ----
#define WS_FEATT  0                 // float [B*N2*CIN]             2097152
#define WS_OUT2   2097152           // float [B*COUT*N1]            1048576
#define WS_CNT    3145728           // int   [B*1024] cell counts      4096
#define WS_BPTS   3149824           // float4[B*1024*CAP] binned     655360

__device__ __forceinline__ int cell_of(float x, float y, float z) {
  int cx = (int)(x*10.f); cx = cx < 0 ? 0 : (cx > 9 ? 9 : cx);
  int cy = (int)(y*10.f); cy = cy < 0 ? 0 : (cy > 9 ? 9 : cy);
  int cz = (int)(z*10.f); cz = cz < 0 ? 0 : (cz > 9 ? 9 : cz);
  return (cx*10 + cy)*10 + cz;
}

// ---------------------------------------------------------------------------
// prep: blocks 0-511 feature transpose (LDS-tiled);
//       blocks 512-639 direct fixed-capacity binning (atomic slot claim).
// grid = 640 x 256.
// ---------------------------------------------------------------------------
__global__ __launch_bounds__(256) void pg_prep(
    const float* __restrict__ sxyz, const float* __restrict__ smask,
    const float* __restrict__ sfeat, float* __restrict__ featT,
    int* __restrict__ cellCnt, float4* __restrict__ bpts)
{
  __shared__ float tile[64*65];
  const int t  = threadIdx.x;
  const int bt = blockIdx.x;

  if (bt >= 512) {        // ---- binning: 1 point per thread ----
    const int idx = bt - 512;                // [0,128)
    const int bb  = idx >> 5;
    const int i   = ((idx & 31) << 8) + t;   // [0,8192)
    if (smask[bb*N2D + i] > 0.f) {
      const float* p = sxyz + ((size_t)bb*N2D + i)*3;
      const float px = p[0], py = p[1], pz = p[2];
      const int cell = bb*1024 + cell_of(px, py, pz);
      const int pos = atomicAdd(&cellCnt[cell], 1);
      if (pos < CAP)
        bpts[(size_t)cell*CAP + pos] = make_float4(px, py, pz, __int_as_float(i));
    }
    return;
  }

  // ---- feature transpose tile ----
  const int b  = bt >> 7;
  const int j0 = (bt & 127) * 64;
  const float* src = sfeat + (size_t)(b*CIN)*N2D + j0;
#pragma unroll
  for (int i = 0; i < 4; ++i) {
    const int c  = i*16 + (t >> 4);
    const int j4 = (t & 15) * 4;
    const float4 v = *(const float4*)(src + (size_t)c*N2D + j4);
    tile[c*65 + j4+0] = v.x;
    tile[c*65 + j4+1] = v.y;
    tile[c*65 + j4+2] = v.z;
    tile[c*65 + j4+3] = v.w;
  }
  __syncthreads();
  float* dstb = featT + (size_t)(b*N2D + j0) * CIN;
#pragma unroll
  for (int r = 0; r < 4; ++r) {
    const int j  = r*16 + (t >> 4);
    const int c4 = (t & 15) * 4;
    float4 v;
    v.x = tile[(c4+0)*65 + j];
    v.y = tile[(c4+1)*65 + j];
    v.z = tile[(c4+2)*65 + j];
    v.w = tile[(c4+3)*65 + j];
    *(float4*)(dstb + j*CIN + c4) = v;
  }
}

// ---------------------------------------------------------------------------
// main: cell-walk ordered ball query + dense branchless kernel-point weights
// + weighted feature sum + fused 1x1 conv.  grid = 2048 x 256 (1 query/wave).
// Wave-local phases; single barrier before epilogue.  LDS ~19.2 KB.
// ---------------------------------------------------------------------------
__global__ __launch_bounds__(256) void pg_main(
    const float* __restrict__ qxyz, const float* __restrict__ qmask,
    const float4* __restrict__ bpts, const int* __restrict__ cellCnt,
    const float* __restrict__ featT, const float* __restrict__ Kp,
    const float* __restrict__ KW, const float* __restrict__ Wout,
    const float* __restrict__ sxyz, float* __restrict__ out2)
{
  __shared__ __align__(16) float4 s_cand4[QPB][MAXC];  // candidate coords+j
  __shared__ __align__(16) int    s_candj[QPB][MAXC];  // candidate j
  __shared__ __align__(16) float4 s_sel[QPB][NSAMP];   // selected (x,y,z,j)
  __shared__ __align__(16) int    s_j[QPB][NSAMP];     // normalized idx
  __shared__ __align__(16) float  s_w[QPB*NSAMP*WST];  // dense weights 10 KB
  __shared__ float                s_xq[QPB*68];        // conv x rows

  const int t    = threadIdx.x;
  const int lane = t & 63;
  const int wv   = t >> 6;
  const int gbase = blockIdx.x * QPB;        // 2048 % 4 == 0 -> single batch
  const int b     = gbase >> 11;
  const uint64_t lt = (1ull << lane) - 1ull;

  const int g = gbase + wv;                  // this wave's query
  const float qx = qxyz[g*3+0], qy = qxyz[g*3+1], qz = qxyz[g*3+2];

  // ---- phase 1: 3D-pruned per-cell segment walk ----
  int cq;
  {
    int cx0 = (int)((qx-CMARG)*10.f); if (cx0 < 0) cx0 = 0;
    int cx1 = (int)((qx+CMARG)*10.f); if (cx1 > 9) cx1 = 9;
    int cy0 = (int)((qy-CMARG)*10.f); if (cy0 < 0) cy0 = 0;
    int cy1 = (int)((qy+CMARG)*10.f); if (cy1 > 9) cy1 = 9;
    int cz0 = (int)((qz-CMARG)*10.f); if (cz0 < 0) cz0 = 0;
    int cz1 = (int)((qz+CMARG)*10.f); if (cz1 > 9) cz1 = 9;
    const int nz  = cz1 - cz0 + 1;
    const int nyz = (cy1 - cy0 + 1) * nz;
    const int ncl = (cx1 - cx0 + 1) * nyz;   // <= 27

    int len = 0, base = 0;
    if (lane < ncl) {
      int r = lane;
      const int cx = cx0 + r / nyz;  r %= nyz;
      const int cy = cy0 + r / nz;
      const int cz = cz0 + r % nz;
      // 3D AABB prune: min distance from q to cell box
      const float lox = cx*0.1f, loy = cy*0.1f, loz = cz*0.1f;
      const float dxc = fmaxf(fmaxf(lox - qx, qx - (lox+0.1f)), 0.f);
      const float dyc = fmaxf(fmaxf(loy - qy, qy - (loy+0.1f)), 0.f);
      const float dzc = fmaxf(fmaxf(loz - qz, qz - (loz+0.1f)), 0.f);
      if (dxc*dxc + dyc*dyc + dzc*dzc < RAD2) {
        const int cell = b*1024 + (cx*10 + cy)*10 + cz;
        const int cnt = cellCnt[cell];        // L2-hot 16 KB
        len  = cnt < CAP ? cnt : CAP;
        base = cell*CAP;
      }
    }
    int pc = len;                            // inclusive prefix over 64 lanes
#pragma unroll
    for (int off = 1; off < 64; off <<= 1) {
      int y = __shfl_up(pc, off);
      if (lane >= off) pc += y;
    }
    const int tot  = __shfl(pc, 63);
    const int excl = pc - len;
    const int sb   = base - excl;

    // broadcast 27-entry segment tables to SGPRs
    int segc[27], segb[27];
#pragma unroll
    for (int e = 0; e < 27; ++e) {
      const int ce = __builtin_amdgcn_readlane(excl, e);
      const int be = __builtin_amdgcn_readlane(sb,   e);
      segc[e] = (e < ncl) ? ce : INT_MAX;
      segb[e] = (e < ncl) ? be : 0;
    }

    int ccnt = 0;
    for (int base0 = 0; base0 < tot; base0 += 64*NPF) {
      float4 pt[NPF];
#pragma unroll
      for (int u = 0; u < NPF; ++u) {
        const int idx = base0 + u*64 + lane;
        if (idx < tot) {
          int bb2 = segb[0];                 // branchless segment select
#pragma unroll
          for (int e = 1; e < 27; ++e) if (segc[e] <= idx) bb2 = segb[e];
          pt[u] = bpts[bb2 + idx];
        }
      }
#pragma unroll
      for (int u = 0; u < NPF; ++u) {
        const int idx = base0 + u*64 + lane;
        bool ok = false;
        if (idx < tot) {
          const float dx = pt[u].x - qx, dy = pt[u].y - qy, dz = pt[u].z - qz;
          ok = (dx*dx + dy*dy + dz*dz) < RAD2;
        }
        const uint64_t m = __ballot(ok);
        if (ok) {
          const int pos = ccnt + __popcll(m & lt);
          if (pos < MAXC) {
            s_cand4[wv][pos] = pt[u];
            s_candj[wv][pos] = __float_as_int(pt[u].w);
          }
        }
        ccnt += (int)__popcll(m);
      }
    }
    const int C = ccnt < MAXC ? ccnt : MAXC;
    const int C4 = (C + 3) & ~3;
    if (C + lane < C4) s_candj[wv][C + lane] = INT_MAX;  // pad to x4

    // rank-select 32 smallest j via int4 LDS reads
    const int jA = (lane      < C) ? s_candj[wv][lane]      : INT_MAX;
    const int jB = (lane + 64 < C) ? s_candj[wv][lane + 64] : INT_MAX;
    int rA = 0, rB = 0;
    for (int e = 0; e < C4; e += 4) {
      const int4 v4 = *(const int4*)&s_candj[wv][e];
      rA += (v4.x < jA) + (v4.y < jA) + (v4.z < jA) + (v4.w < jA);
      rB += (v4.x < jB) + (v4.y < jB) + (v4.z < jB) + (v4.w < jB);
    }
    if (lane      < C && rA < NSAMP) s_sel[wv][rA] = s_cand4[wv][lane];
    if (lane + 64 < C && rB < NSAMP) s_sel[wv][rB] = s_cand4[wv][lane + 64];
    cq = C < NSAMP ? C : NSAMP;
  }

  // ---- phase 2-pre (wave-local): pad-normalize slots, publish s_j ----
  {
    const int s    = lane & 31;
    const int half = lane >> 5;
    float4 sel;
    if (cq > 0) {
      sel = s_sel[wv][s < cq ? s : 0];       // pad with first (min-j) neighbor
    } else {
      sel = make_float4(sxyz[(size_t)b*N2D*3+0], sxyz[(size_t)b*N2D*3+1],
                        sxyz[(size_t)b*N2D*3+2], __int_as_float(0));
    }
    if (half == 0) {
      s_sel[wv][s] = sel;                    // normalized coords for weights
      s_j[wv][s]   = __float_as_int(sel.w);
    }
  }

  // ---- issue all 32 feature gathers EARLY (overlap the weight math) ----
  float ft[NSAMP];
#pragma unroll
  for (int s = 0; s < NSAMP; ++s) {
    const int j = __builtin_amdgcn_readfirstlane(s_j[wv][s]);
    ft[s] = featT[(size_t)(b*N2D + j)*CIN + lane];
  }

  // ---- phase 2a (wave-local): dense weight rows ----
  {
    const int s    = lane & 31;
    const int half = lane >> 5;
    const float4 sel = s_sel[wv][s];
    const float rx = sel.x - qx;
    const float ry = sel.y - qy;
    const float rz = sel.z - qz;

    float w[8];
#pragma unroll
    for (int ki = 0; ki < 8; ++ki) {
      const int k  = half*8 + ki;
      const int kc = k < NKP-1 ? k : NKP-1;  // clamp for safe Kp read
      const float dx = rx - Kp[kc*3+0];
      const float dy = ry - Kp[kc*3+1];
      const float dz = rz - Kp[kc*3+2];
      float wk = fmaxf(1.0f - sqrtf(dx*dx+dy*dy+dz*dz)*INV_EXT, 0.0f);
      w[ki] = (k < NKP) ? wk : 0.0f;         // slot 15 = exact 0
    }
    float4* wrow = (float4*)&s_w[(wv*NSAMP + s)*WST + half*8];
    wrow[0] = make_float4(w[0], w[1], w[2], w[3]);
    wrow[1] = make_float4(w[4], w[5], w[6], w[7]);
  }

  // ---- phase 2b (wave-local, branchless): weighted feature aggregation ----
  {
    float kw[16];
#pragma unroll
    for (int k = 0; k < NKP; ++k) kw[k] = KW[k*CIN + lane];
    kw[15] = 0.0f;

    const float fpad = 1.0f - qmask[g];
    const int cqs = __builtin_amdgcn_readfirstlane(cq);

    float acc = 0.0f;
#pragma unroll
    for (int s = 0; s < NSAMP; ++s) {
      const float fm = ((s < cqs) ? 1.0f : 0.0f) + fpad;
      const float4* wp = (const float4*)&s_w[(wv*NSAMP + s)*WST];
      const float4 w0 = wp[0], w1 = wp[1], w2 = wp[2], w3 = wp[3];
      float wsum;
      wsum = w0.x*kw[0];
      wsum = fmaf(w0.y, kw[1],  wsum);
      wsum = fmaf(w0.z, kw[2],  wsum);
      wsum = fmaf(w0.w, kw[3],  wsum);
      wsum = fmaf(w1.x, kw[4],  wsum);
      wsum = fmaf(w1.y, kw[5],  wsum);
      wsum = fmaf(w1.z, kw[6],  wsum);
      wsum = fmaf(w1.w, kw[7],  wsum);
      wsum = fmaf(w2.x, kw[8],  wsum);
      wsum = fmaf(w2.y, kw[9],  wsum);
      wsum = fmaf(w2.z, kw[10], wsum);
      wsum = fmaf(w2.w, kw[11], wsum);
      wsum = fmaf(w3.x, kw[12], wsum);
      wsum = fmaf(w3.y, kw[13], wsum);
      wsum = fmaf(w3.z, kw[14], wsum);
      wsum = fmaf(w3.w, kw[15], wsum);
      acc = fmaf(fm*wsum, ft[s], acc);
    }
    s_xq[wv*68 + lane] = acc;
  }
  __syncthreads();                           // the ONLY block barrier

  // ---- epilogue: fused 1x1 conv, 256 threads x 2 outputs, b128 reads ----
  // thread t: query slot n4 = t&3, o-pair og = t>>2 -> 16B write segments
  {
    const int n4 = t & 3;
    const int og = t >> 2;
    const int gq = gbase + n4;
    const int nn = gq & 2047;
    const float4* xr = (const float4*)&s_xq[n4*68];
    const float4* w0 = (const float4*)(Wout + (og*2+0)*CIN);
    const float4* w1 = (const float4*)(Wout + (og*2+1)*CIN);
    float a0 = 0.f, a1 = 0.f;
#pragma unroll
    for (int c4 = 0; c4 < 16; ++c4) {
      const float4 x4 = xr[c4];
      const float4 wa = w0[c4];
      const float4 wb = w1[c4];
      a0 = fmaf(wa.x, x4.x, fmaf(wa.y, x4.y, fmaf(wa.z, x4.z, fmaf(wa.w, x4.w, a0))));
      a1 = fmaf(wb.x, x4.x, fmaf(wb.y, x4.y, fmaf(wb.z, x4.z, fmaf(wb.w, x4.w, a1))));
    }
    float* ob = out2 + (size_t)(b*COUT + og*2)*N1D + nn;
    ob[0]   = a0;
    ob[N1D] = a1;
  }
}

// ---------------------------------------------------------------------------
// finish: per-(b,o) block; redundant stats + normalize own row.  512 x 256.
// ---------------------------------------------------------------------------
__global__ __launch_bounds__(256) void pg_finish(
    const float* __restrict__ out2, const float* __restrict__ gamma,
    const float* __restrict__ beta, float* __restrict__ dout)
{
  __shared__ float red[8];
  __shared__ float mv[2];
  const int t  = threadIdx.x;
  const int o  = blockIdx.x & 127;
  const int bb = blockIdx.x >> 7;
  float4 f[4][2];
  float s1 = 0.f, s2 = 0.f;
#pragma unroll
  for (int r = 0; r < BATCH; ++r) {
    const float4* p = (const float4*)(out2 + (size_t)(r*COUT + o)*N1D);
#pragma unroll
    for (int i = 0; i < 2; ++i) {
      const float4 x = p[i*256 + t];
      f[r][i] = x;
      s1 += x.x + x.y + x.z + x.w;
      s2 += x.x*x.x + x.y*x.y + x.z*x.z + x.w*x.w;
    }
  }
#pragma unroll
  for (int off = 32; off; off >>= 1) {
    s1 += __shfl_xor(s1, off);
    s2 += __shfl_xor(s2, off);
  }
  const int wv = t >> 6;
  if ((t & 63) == 0) { red[wv] = s1; red[4+wv] = s2; }
  __syncthreads();
  if (t == 0) {
    const float inv = 1.0f / (float)(BATCH*N1D);
    const float mean = (red[0]+red[1]+red[2]+red[3]) * inv;
    const float var  = (red[4]+red[5]+red[6]+red[7]) * inv - mean*mean;
    mv[0] = mean;
    mv[1] = rsqrtf(var + BN_EPS);
  }
  __syncthreads();
  const float mean = mv[0];
  const float ga = gamma[o] * mv[1];
  const float be = beta[o];
  float4* dp = (float4*)(dout + (size_t)(bb*COUT + o)*N1D);
#pragma unroll
  for (int i = 0; i < 2; ++i) {
    const float4 x = f[bb][i];
    float4 y;
    y.x = fmaxf((x.x - mean)*ga + be, 0.0f);
    y.y = fmaxf((x.y - mean)*ga + be, 0.0f);
    y.z = fmaxf((x.z - mean)*ga + be, 0.0f);
    y.w = fmaxf((x.w - mean)*ga + be, 0.0f);
    dp[i*256 + t] = y;
  }
}

extern "C" void kernel_launch(void* const* d_in, const int* in_sizes, int n_in,
                              void* d_out, int out_size, void* d_ws, size_t ws_size,
                              hipStream_t stream)
{
  const float* qxyz  = (const float*)d_in[0];
  const float* sxyz  = (const float*)d_in[1];
  const float* qmask = (const float*)d_in[2];
  const float* smask = (const float*)d_in[3];
  const float* sfeat = (const float*)d_in[4];
  const float* Kp    = (const float*)d_in[5];
  const float* KW    = (const float*)d_in[6];
  const float* Wout  = (const float*)d_in[7];
  const float* gamma = (const float*)d_in[8];
  const float* beta  = (const float*)d_in[9];
  float* ws = (float*)d_ws;
  float*  featT = ws + WS_FEATT;
  float*  out2  = ws + WS_OUT2;
  int*    cellC = (int*)(ws + WS_CNT);
  float4* bpts  = (float4*)(ws + WS_BPTS);
  float* dst    = (float*)d_out;

  hipMemsetAsync(cellC, 0, BATCH*1024*sizeof(int), stream);
  pg_prep  <<<640,  256, 0, stream>>>(sxyz, smask, sfeat, featT, cellC, bpts);
  pg_main  <<<2048, 256, 0, stream>>>(qxyz, qmask, bpts, cellC, featT,
                                      Kp, KW, Wout, sxyz, out2);
  pg_finish<<<512,  256, 0, stream>>>(out2, gamma, beta, dst);
}